// Round 1
// baseline (211.673 us; speedup 1.0000x reference)
//
#include <hip/hip_runtime.h>
#include <hip/hip_bf16.h>
#include <hip/hip_fp16.h>

#define DEVI __device__ __forceinline__

typedef _Float16 f16x8 __attribute__((ext_vector_type(8)));
typedef float f32x4 __attribute__((ext_vector_type(4)));

static constexpr int M = 32768;   // batch
static constexpr int N = 1024;    // H21
static constexpr int K = 2048;    // H1
static constexpr int BM = 128, BN = 128, BK = 32;
static constexpr int NT = K / BK;        // 64 k-steps
static constexpr int NSTRIP = (N / BN) * 2;  // 16 partial strips

// ---- ws layout ----
static constexpr size_t WS_H    = 0;                       // f16 [M][K]   = 134217728 B
static constexpr size_t WS_W21T = 134217728;               // f16 [N][K]   = 4194304 B
static constexpr size_t WS_PART = 134217728 + 4194304;     // f32 [16][M][2] = 4194304 B

using lds_vp = __attribute__((address_space(3))) void*;
using gbl_vp = const __attribute__((address_space(1))) void*;

DEVI void async_ld16(const void* g, void* l) {
  __builtin_amdgcn_global_load_lds((gbl_vp)(size_t)g,
                                   (lds_vp)(uint32_t)(size_t)l,
                                   16, 0, 0);
}

// ---------- prep: W21 [K][N] fp32 -> W21^T [N][K] f16 ----------
__global__ __launch_bounds__(256)
void w21cvt_kernel(const float* __restrict__ W21, _Float16* __restrict__ w21t) {
  __shared__ float sT[64][65];
  const int tid = threadIdx.x;
  const int k0 = blockIdx.x * 64;   // 32
  const int n0 = blockIdx.y * 64;   // 16
  const int row = tid >> 2;
#pragma unroll
  for (int q = 0; q < 4; ++q) {
    int c = (tid & 3) * 4 + q * 16;
    float4 v = *(const float4*)(W21 + (size_t)(k0 + row) * 1024 + n0 + c);
    sT[row][c + 0] = v.x; sT[row][c + 1] = v.y;
    sT[row][c + 2] = v.z; sT[row][c + 3] = v.w;
  }
  __syncthreads();
  const int n  = tid >> 2;
  const int kc = (tid & 3) * 16;
  union { _Float16 h[16]; float4 f4[2]; } u;
#pragma unroll
  for (int e = 0; e < 16; ++e) u.h[e] = (_Float16)sT[kc + e][n];
  float4* dst = (float4*)(w21t + (size_t)(n0 + n) * 2048 + k0 + kc);
  dst[0] = u.f4[0]; dst[1] = u.f4[1];
}

// ---------- gemm1: h = relu(x@W1 + b1), fp32 math, f16 out ----------
__global__ __launch_bounds__(256)
void gemm1_kernel(const float* __restrict__ x, const float* __restrict__ W1,
                  const float* __restrict__ b1, _Float16* __restrict__ hout) {
  __shared__ float sx[64 * 8];
  const int tid = threadIdx.x;
  const int r0 = blockIdx.x * 64;
  if (tid < 128) {
    *(float4*)&sx[tid * 4] = *(const float4*)(x + (size_t)r0 * 8 + tid * 4);
  }
  float w1r[8][8];
#pragma unroll
  for (int j = 0; j < 8; ++j) {
    *(float4*)&w1r[j][0] = *(const float4*)(W1 + j * 2048 + tid * 8);
    *(float4*)&w1r[j][4] = *(const float4*)(W1 + j * 2048 + tid * 8 + 4);
  }
  float bb[8];
  *(float4*)&bb[0] = *(const float4*)(b1 + tid * 8);
  *(float4*)&bb[4] = *(const float4*)(b1 + tid * 8 + 4);
  __syncthreads();
  for (int r = 0; r < 64; ++r) {
    float xv[8];
    *(float4*)&xv[0] = *(float4*)&sx[r * 8];
    *(float4*)&xv[4] = *(float4*)&sx[r * 8 + 4];
    float acc[8];
#pragma unroll
    for (int c = 0; c < 8; ++c) acc[c] = bb[c];
#pragma unroll
    for (int j = 0; j < 8; ++j)
#pragma unroll
      for (int c = 0; c < 8; ++c) acc[c] = fmaf(xv[j], w1r[j][c], acc[c]);
    union { f16x8 v; float4 f4; } u;
#pragma unroll
    for (int c = 0; c < 8; ++c) u.v[c] = (_Float16)fmaxf(acc[c], 0.f);
    *(float4*)(hout + (size_t)(r0 + r) * 2048 + tid * 8) = u.f4;
  }
}

// ---------- gemm2: a = relu(h@W21+b21); partial[strip][row][2] = a @ W31 ----------
__global__ __launch_bounds__(256, 2)
void gemm2_kernel(const _Float16* __restrict__ h, const _Float16* __restrict__ w21t,
                  const float* __restrict__ b21, const float* __restrict__ w31,
                  float* __restrict__ part) {
  __shared__ __align__(16) _Float16 sA[2][BM * BK];
  __shared__ __align__(16) _Float16 sB[2][BM * BK];
  const int tid  = threadIdx.x;
  const int lane = tid & 63;
  const int w    = tid >> 6;
  const int wr   = w >> 1, wc = w & 1;
  const int r0 = blockIdx.x * BM;
  const int n0 = blockIdx.y * BN;

  f32x4 acc[4][4] = {};

  // staging: thread covers row (tid>>2), 8 f16 at col (tid&3)*8; 2 issues of 64 rows
  const int srow = tid >> 2;
  const int scol = (tid & 3) * 8;
  const _Float16* gA = h    + (size_t)(r0 + srow) * K + scol;
  const _Float16* gB = w21t + (size_t)(n0 + srow) * K + scol;

  auto stage = [&](int buf, int t) {
    const int k0 = t * BK;
#pragma unroll
    for (int i = 0; i < 2; ++i) {
      async_ld16(gA + (size_t)i * 64 * K + k0, (char*)&sA[buf][0] + i * 4096 + tid * 16);
      async_ld16(gB + (size_t)i * 64 * K + k0, (char*)&sB[buf][0] + i * 4096 + tid * 16);
    }
  };

  const int arow = wr * 64 + (lane & 15);
  const int brow = wc * 64 + (lane & 15);
  const int koff = (lane >> 4) * 8;

  stage(0, 0);
  for (int t = 0; t < NT; ++t) {
    __syncthreads();                    // drains vmcnt -> staged data visible
    if (t + 1 < NT) stage((t + 1) & 1, t + 1);
    const _Float16* pa = &sA[t & 1][0];
    const _Float16* pb = &sB[t & 1][0];
    f16x8 aF[4], bF[4];
#pragma unroll
    for (int m = 0; m < 4; ++m) aF[m] = *(const f16x8*)(pa + (arow + m * 16) * BK + koff);
#pragma unroll
    for (int n = 0; n < 4; ++n) bF[n] = *(const f16x8*)(pb + (brow + n * 16) * BK + koff);
#pragma unroll
    for (int m = 0; m < 4; ++m)
#pragma unroll
      for (int n = 0; n < 4; ++n)
        acc[m][n] = __builtin_amdgcn_mfma_f32_16x16x32_f16(aF[m], bF[n], acc[m][n], 0, 0, 0);
  }

  // epilogue: a = relu(acc + b21); s = a @ W31[cols,2]; reduce 16 lanes -> row sums
  float bb[4], w0v[4], w1v[4];
#pragma unroll
  for (int n = 0; n < 4; ++n) {
    int cg = n0 + wc * 64 + n * 16 + (lane & 15);
    bb[n]  = b21[cg];
    w0v[n] = w31[cg * 2 + 0];
    w1v[n] = w31[cg * 2 + 1];
  }
  const int strip = blockIdx.y * 2 + wc;
#pragma unroll
  for (int m = 0; m < 4; ++m) {
#pragma unroll
    for (int j = 0; j < 4; ++j) {
      float s0 = 0.f, s1 = 0.f;
#pragma unroll
      for (int n = 0; n < 4; ++n) {
        float a = fmaxf(acc[m][n][j] + bb[n], 0.f);
        s0 = fmaf(a, w0v[n], s0);
        s1 = fmaf(a, w1v[n], s1);
      }
#pragma unroll
      for (int d = 1; d < 16; d <<= 1) {
        s0 += __shfl_xor(s0, d, 64);
        s1 += __shfl_xor(s1, d, 64);
      }
      if ((lane & 15) == 0) {
        int gr = r0 + wr * 64 + m * 16 + (lane >> 4) * 4 + j;
        float2 v; v.x = s0; v.y = s1;
        *(float2*)(part + ((size_t)strip * M + gr) * 2) = v;
      }
    }
  }
}

// ---------- final: sum strips, add b31, QP clip, de/normalize ----------
__global__ __launch_bounds__(256)
void final_kernel(const float* __restrict__ part, const float* __restrict__ b31,
                  const float* __restrict__ om, const float* __restrict__ os,
                  const float* __restrict__ s0p, const float* __restrict__ s1p,
                  const float* __restrict__ s2p, const float* __restrict__ s3p,
                  float* __restrict__ out) {
  const int r = blockIdx.x * blockDim.x + threadIdx.x;
  float a0 = b31[0], a1 = b31[1];
#pragma unroll
  for (int s = 0; s < NSTRIP; ++s) {
    float2 v = *(const float2*)(part + ((size_t)s * M + r) * 2);
    a0 += v.x; a1 += v.y;
  }
  const float om0 = om[0], om1 = om[1], os0 = os[0], os1 = os[1];
  const float xa0 = a0 * os0 + om0;
  const float xa1 = a1 * os1 + om1;
  const float up0 = 1.0f + s2p[0];            // OMEGA_LIMIT + s2
  const float up1 = 1.0f + s0p[0];            // ACCEL_LIMIT + s0
  const float lo0 = -(1.0f + s3p[0]);
  const float lo1 = -(1.0f + s1p[0]);
  const float u0 = fminf(fmaxf(-xa0, lo0), up0);
  const float u1 = fminf(fmaxf(-xa1, lo1), up1);
  float2 o; o.x = (u0 - om0) / os0; o.y = (u1 - om1) / os1;
  *(float2*)(out + (size_t)r * 2) = o;
}

extern "C" void kernel_launch(void* const* d_in, const int* in_sizes, int n_in,
                              void* d_out, int out_size, void* d_ws, size_t ws_size,
                              hipStream_t stream) {
  const float* x    = (const float*)d_in[0];
  const float* W1   = (const float*)d_in[1];
  const float* b1   = (const float*)d_in[2];
  const float* W21  = (const float*)d_in[3];
  const float* b21  = (const float*)d_in[4];
  const float* W31  = (const float*)d_in[5];
  const float* b31  = (const float*)d_in[6];
  const float* omean = (const float*)d_in[13];
  const float* ostd  = (const float*)d_in[14];
  const float* s0 = (const float*)d_in[15];
  const float* s1 = (const float*)d_in[16];
  const float* s2 = (const float*)d_in[17];
  const float* s3 = (const float*)d_in[18];
  float* out = (float*)d_out;

  char* ws = (char*)d_ws;
  _Float16* hbuf = (_Float16*)(ws + WS_H);
  _Float16* w21t = (_Float16*)(ws + WS_W21T);
  float*    part = (float*)(ws + WS_PART);

  w21cvt_kernel<<<dim3(32, 16), dim3(256), 0, stream>>>(W21, w21t);
  gemm1_kernel<<<dim3(512), dim3(256), 0, stream>>>(x, W1, b1, hbuf);
  gemm2_kernel<<<dim3(M / BM, N / BN), dim3(256), 0, stream>>>(hbuf, w21t, b21, W31, part);
  final_kernel<<<dim3(M / 256), dim3(256), 0, stream>>>(part, b31, omean, ostd,
                                                        s0, s1, s2, s3, out);
}

// Round 2
// 172.497 us; speedup vs baseline: 1.2271x; 1.2271x over previous
//
#include <hip/hip_runtime.h>
#include <hip/hip_bf16.h>
#include <hip/hip_fp16.h>

#define DEVI __device__ __forceinline__

typedef _Float16 f16x8 __attribute__((ext_vector_type(8)));
typedef float f32x4 __attribute__((ext_vector_type(4)));

static constexpr int M = 32768;   // batch
static constexpr int N = 1024;    // H21
static constexpr int K = 2048;    // H1
static constexpr int BM = 256, BN = 256, BK = 32;
static constexpr int NT = K / BK;            // 64 k-tiles
static constexpr int NSTRIP = (N / BN) * 4;  // 16 partial strips (4 nblk x 4 wc)

// ---- ws layout ----
static constexpr size_t WS_H    = 0;                       // f16 [M][K]   = 134217728 B
static constexpr size_t WS_W21T = 134217728;               // f16 [N][K]   = 4194304 B
static constexpr size_t WS_PART = 134217728 + 4194304;     // f32 [16][M][2] = 4194304 B

using lds_vp = __attribute__((address_space(3))) void*;
using gbl_vp = const __attribute__((address_space(1))) void*;

DEVI void async_ld16(const void* g, void* l) {
  __builtin_amdgcn_global_load_lds((gbl_vp)(size_t)g,
                                   (lds_vp)(uint32_t)(size_t)l,
                                   16, 0, 0);
}

// ---------- prep: W21 [K][N] fp32 -> W21^T [N][K] f16 ----------
__global__ __launch_bounds__(256)
void w21cvt_kernel(const float* __restrict__ W21, _Float16* __restrict__ w21t) {
  __shared__ float sT[64][65];
  const int tid = threadIdx.x;
  const int k0 = blockIdx.x * 64;   // 32
  const int n0 = blockIdx.y * 64;   // 16
  const int row = tid >> 2;
#pragma unroll
  for (int q = 0; q < 4; ++q) {
    int c = (tid & 3) * 4 + q * 16;
    float4 v = *(const float4*)(W21 + (size_t)(k0 + row) * 1024 + n0 + c);
    sT[row][c + 0] = v.x; sT[row][c + 1] = v.y;
    sT[row][c + 2] = v.z; sT[row][c + 3] = v.w;
  }
  __syncthreads();
  const int n  = tid >> 2;
  const int kc = (tid & 3) * 16;
  union { _Float16 h[16]; float4 f4[2]; } u;
#pragma unroll
  for (int e = 0; e < 16; ++e) u.h[e] = (_Float16)sT[kc + e][n];
  float4* dst = (float4*)(w21t + (size_t)(n0 + n) * 2048 + k0 + kc);
  dst[0] = u.f4[0]; dst[1] = u.f4[1];
}

// ---------- gemm1: h = relu(x@W1 + b1), fp32 math, f16 out ----------
__global__ __launch_bounds__(256)
void gemm1_kernel(const float* __restrict__ x, const float* __restrict__ W1,
                  const float* __restrict__ b1, _Float16* __restrict__ hout) {
  __shared__ float sx[64 * 8];
  const int tid = threadIdx.x;
  const int r0 = blockIdx.x * 64;
  if (tid < 128) {
    *(float4*)&sx[tid * 4] = *(const float4*)(x + (size_t)r0 * 8 + tid * 4);
  }
  float w1r[8][8];
#pragma unroll
  for (int j = 0; j < 8; ++j) {
    *(float4*)&w1r[j][0] = *(const float4*)(W1 + j * 2048 + tid * 8);
    *(float4*)&w1r[j][4] = *(const float4*)(W1 + j * 2048 + tid * 8 + 4);
  }
  float bb[8];
  *(float4*)&bb[0] = *(const float4*)(b1 + tid * 8);
  *(float4*)&bb[4] = *(const float4*)(b1 + tid * 8 + 4);
  __syncthreads();
  for (int r = 0; r < 64; ++r) {
    float xv[8];
    *(float4*)&xv[0] = *(float4*)&sx[r * 8];
    *(float4*)&xv[4] = *(float4*)&sx[r * 8 + 4];
    float acc[8];
#pragma unroll
    for (int c = 0; c < 8; ++c) acc[c] = bb[c];
#pragma unroll
    for (int j = 0; j < 8; ++j)
#pragma unroll
      for (int c = 0; c < 8; ++c) acc[c] = fmaf(xv[j], w1r[j][c], acc[c]);
    union { f16x8 v; float4 f4; } u;
#pragma unroll
    for (int c = 0; c < 8; ++c) u.v[c] = (_Float16)fmaxf(acc[c], 0.f);
    *(float4*)(hout + (size_t)(r0 + r) * 2048 + tid * 8) = u.f4;
  }
}

// ---------- gemm2: 256x256 tile, BK=32, 4-buffer pipeline, counted vmcnt ----------
// a = relu(h@W21+b21); partial[strip][row][2] = a @ W31
__global__ __launch_bounds__(512, 2)
void gemm2_kernel(const _Float16* __restrict__ h, const _Float16* __restrict__ w21t,
                  const float* __restrict__ b21, const float* __restrict__ w31,
                  float* __restrict__ part) {
  // 4 buffers x (A 256x32 + B 256x32) f16 = 128 KiB
  __shared__ __align__(16) _Float16 sA[4 * BM * BK];
  __shared__ __align__(16) _Float16 sB[4 * BN * BK];

  const int tid  = threadIdx.x;
  const int lane = tid & 63;
  const int w    = tid >> 6;      // 0..7
  const int wr   = w >> 2;        // 0..1 -> 128 rows each
  const int wc   = w & 3;         // 0..3 -> 64 cols each

  // XCD-chunked bijective swizzle: 512 wg, 8 XCD, 64/chunk; n-block fastest
  const int lin  = blockIdx.x;
  const int swz  = (lin & 7) * 64 + (lin >> 3);
  const int nblk = swz & 3;
  const int mblk = swz >> 2;
  const int r0 = mblk * BM;
  const int n0 = nblk * BN;

  f32x4 acc[8][4] = {};

  // ---- staging addresses (pre-swizzled global source, linear LDS dest) ----
  // LDS linear byte (per buffer) = j*8192 + tid*16  <->  row r = j*128 + (tid>>2),
  // slot c' = tid&3; source chunk c = c' ^ (r[3:2])  (same for j=0,1).
  const int sr  = tid >> 2;
  const int scp = tid & 3;
  const int sc  = scp ^ ((sr >> 2) & 3);
  const _Float16* gAb = h    + (size_t)(r0 + sr) * K + sc * 8;
  const _Float16* gBb = w21t + (size_t)(n0 + sr) * K + sc * 8;
  char* const lA0 = (char*)&sA[0] + tid * 16;
  char* const lB0 = (char*)&sB[0] + tid * 16;

  auto stageA = [&](int tt) {
    const int b = tt & 3;
    const _Float16* g = gAb + tt * BK;
    async_ld16(g,                    lA0 + b * 16384);
    async_ld16(g + (size_t)128 * K,  lA0 + b * 16384 + 8192);
  };
  auto stageB = [&](int tt) {
    const int b = tt & 3;
    const _Float16* g = gBb + tt * BK;
    async_ld16(g,                    lB0 + b * 16384);
    async_ld16(g + (size_t)128 * K,  lB0 + b * 16384 + 8192);
  };

  // ---- ds_read addresses (swizzled) ----
  const int arow  = wr * 128 + (lane & 15);
  const int brow  = wc * 64  + (lane & 15);
  const int klo   = lane >> 4;                       // 16B chunk 0..3
  const int abyte = arow * 64 + ((klo ^ ((arow >> 2) & 3)) * 16);  // +m*1024
  const int bbyte = brow * 64 + ((klo ^ ((brow >> 2) & 3)) * 16);  // +n*1024

  // ---- prologue: stage tiles 0,1,2 ----
  stageA(0); stageB(0);
  stageA(1); stageB(1);
  stageA(2); stageB(2);
  asm volatile("s_waitcnt vmcnt(8)" ::: "memory");   // tile 0 resident
  __builtin_amdgcn_s_barrier();

  for (int t = 0; t < NT; ++t) {
    const int buf = t & 3;
    const char* pA = (const char*)&sA[0] + buf * 16384;
    const char* pB = (const char*)&sB[0] + buf * 16384;

    // ---- phase 0: read A(8) + B(2); stage A(t+3); MFMA n0,n1 ----
    f16x8 aF[8], bF[4];
#pragma unroll
    for (int m = 0; m < 8; ++m) aF[m] = *(const f16x8*)(pA + abyte + m * 1024);
    bF[0] = *(const f16x8*)(pB + bbyte);
    bF[1] = *(const f16x8*)(pB + bbyte + 1024);
    if (t + 3 < NT) stageA(t + 3);
    __builtin_amdgcn_s_barrier();
    asm volatile("s_waitcnt lgkmcnt(0)" ::: "memory");
    __builtin_amdgcn_sched_barrier(0);
    __builtin_amdgcn_s_setprio(1);
#pragma unroll
    for (int m = 0; m < 8; ++m) {
      acc[m][0] = __builtin_amdgcn_mfma_f32_16x16x32_f16(aF[m], bF[0], acc[m][0], 0, 0, 0);
      acc[m][1] = __builtin_amdgcn_mfma_f32_16x16x32_f16(aF[m], bF[1], acc[m][1], 0, 0, 0);
    }
    __builtin_amdgcn_s_setprio(0);
    __builtin_amdgcn_sched_barrier(0);
    __builtin_amdgcn_s_barrier();

    // ---- phase 1: read B(2); stage B(t+3); counted vmcnt; MFMA n2,n3 ----
    bF[2] = *(const f16x8*)(pB + bbyte + 2048);
    bF[3] = *(const f16x8*)(pB + bbyte + 3072);
    if (t + 3 < NT) stageB(t + 3);
    // ledger: outstanding = tiles t+1,t+2,t+3 (4 loads each, per wave)
    if (t < NT - 3)       asm volatile("s_waitcnt vmcnt(8)" ::: "memory");
    else if (t == NT - 3) asm volatile("s_waitcnt vmcnt(4)" ::: "memory");
    else                  asm volatile("s_waitcnt vmcnt(0)" ::: "memory");
    __builtin_amdgcn_s_barrier();
    asm volatile("s_waitcnt lgkmcnt(0)" ::: "memory");
    __builtin_amdgcn_sched_barrier(0);
    __builtin_amdgcn_s_setprio(1);
#pragma unroll
    for (int m = 0; m < 8; ++m) {
      acc[m][2] = __builtin_amdgcn_mfma_f32_16x16x32_f16(aF[m], bF[2], acc[m][2], 0, 0, 0);
      acc[m][3] = __builtin_amdgcn_mfma_f32_16x16x32_f16(aF[m], bF[3], acc[m][3], 0, 0, 0);
    }
    __builtin_amdgcn_s_setprio(0);
    __builtin_amdgcn_sched_barrier(0);
    __builtin_amdgcn_s_barrier();
  }

  // ---- epilogue: a = relu(acc + b21); s = a @ W31; 16-lane reduce; write strip ----
  float bb[4], w0v[4], w1v[4];
#pragma unroll
  for (int n = 0; n < 4; ++n) {
    int cg = n0 + wc * 64 + n * 16 + (lane & 15);
    bb[n]  = b21[cg];
    w0v[n] = w31[cg * 2 + 0];
    w1v[n] = w31[cg * 2 + 1];
  }
  const int strip = nblk * 4 + wc;
#pragma unroll
  for (int m = 0; m < 8; ++m) {
#pragma unroll
    for (int j = 0; j < 4; ++j) {
      float s0 = 0.f, s1 = 0.f;
#pragma unroll
      for (int n = 0; n < 4; ++n) {
        float a = fmaxf(acc[m][n][j] + bb[n], 0.f);
        s0 = fmaf(a, w0v[n], s0);
        s1 = fmaf(a, w1v[n], s1);
      }
#pragma unroll
      for (int d = 1; d < 16; d <<= 1) {
        s0 += __shfl_xor(s0, d, 64);
        s1 += __shfl_xor(s1, d, 64);
      }
      if ((lane & 15) == 0) {
        int gr = r0 + wr * 128 + m * 16 + (lane >> 4) * 4 + j;
        float2 v; v.x = s0; v.y = s1;
        *(float2*)(part + ((size_t)strip * M + gr) * 2) = v;
      }
    }
  }
}

// ---------- final: sum strips, add b31, QP clip, de/normalize ----------
__global__ __launch_bounds__(256)
void final_kernel(const float* __restrict__ part, const float* __restrict__ b31,
                  const float* __restrict__ om, const float* __restrict__ os,
                  const float* __restrict__ s0p, const float* __restrict__ s1p,
                  const float* __restrict__ s2p, const float* __restrict__ s3p,
                  float* __restrict__ out) {
  const int r = blockIdx.x * blockDim.x + threadIdx.x;
  float a0 = b31[0], a1 = b31[1];
#pragma unroll
  for (int s = 0; s < NSTRIP; ++s) {
    float2 v = *(const float2*)(part + ((size_t)s * M + r) * 2);
    a0 += v.x; a1 += v.y;
  }
  const float om0 = om[0], om1 = om[1], os0 = os[0], os1 = os[1];
  const float xa0 = a0 * os0 + om0;
  const float xa1 = a1 * os1 + om1;
  const float up0 = 1.0f + s2p[0];            // OMEGA_LIMIT + s2
  const float up1 = 1.0f + s0p[0];            // ACCEL_LIMIT + s0
  const float lo0 = -(1.0f + s3p[0]);
  const float lo1 = -(1.0f + s1p[0]);
  const float u0 = fminf(fmaxf(-xa0, lo0), up0);
  const float u1 = fminf(fmaxf(-xa1, lo1), up1);
  float2 o; o.x = (u0 - om0) / os0; o.y = (u1 - om1) / os1;
  *(float2*)(out + (size_t)r * 2) = o;
}

extern "C" void kernel_launch(void* const* d_in, const int* in_sizes, int n_in,
                              void* d_out, int out_size, void* d_ws, size_t ws_size,
                              hipStream_t stream) {
  const float* x    = (const float*)d_in[0];
  const float* W1   = (const float*)d_in[1];
  const float* b1   = (const float*)d_in[2];
  const float* W21  = (const float*)d_in[3];
  const float* b21  = (const float*)d_in[4];
  const float* W31  = (const float*)d_in[5];
  const float* b31  = (const float*)d_in[6];
  const float* omean = (const float*)d_in[13];
  const float* ostd  = (const float*)d_in[14];
  const float* s0 = (const float*)d_in[15];
  const float* s1 = (const float*)d_in[16];
  const float* s2 = (const float*)d_in[17];
  const float* s3 = (const float*)d_in[18];
  float* out = (float*)d_out;

  char* ws = (char*)d_ws;
  _Float16* hbuf = (_Float16*)(ws + WS_H);
  _Float16* w21t = (_Float16*)(ws + WS_W21T);
  float*    part = (float*)(ws + WS_PART);

  w21cvt_kernel<<<dim3(32, 16), dim3(256), 0, stream>>>(W21, w21t);
  gemm1_kernel<<<dim3(512), dim3(256), 0, stream>>>(x, W1, b1, hbuf);
  gemm2_kernel<<<dim3((M / BM) * (N / BN)), dim3(512), 0, stream>>>(hbuf, w21t, b21, W31, part);
  final_kernel<<<dim3(M / 256), dim3(256), 0, stream>>>(part, b31, omean, ostd,
                                                        s0, s1, s2, s3, out);
}

// Round 3
// 152.328 us; speedup vs baseline: 1.3896x; 1.1324x over previous
//
#include <hip/hip_runtime.h>
#include <hip/hip_bf16.h>
#include <hip/hip_fp16.h>

#define DEVI __device__ __forceinline__

typedef _Float16 f16x8 __attribute__((ext_vector_type(8)));
typedef float f32x4 __attribute__((ext_vector_type(4)));

static constexpr int M = 32768;   // batch
static constexpr int N = 1024;    // H21
static constexpr int K = 2048;    // H1
static constexpr int BM = 256, BN = 256, BK = 64;
static constexpr int NT = K / BK;            // 32 k-tiles
static constexpr int NSTRIP = (N / BN) * 4;  // 16 partial strips (4 nblk x 4 wc)

// ---- ws layout ----
static constexpr size_t WS_H    = 0;                       // f16 [M][K]   = 134217728 B
static constexpr size_t WS_W21T = 134217728;               // f16 [N][K]   = 4194304 B
static constexpr size_t WS_PART = 134217728 + 4194304;     // f32 [16][M][2] = 4194304 B

using lds_vp = __attribute__((address_space(3))) void*;
using gbl_vp = const __attribute__((address_space(1))) void*;

DEVI void async_ld16(const void* g, void* l) {
  __builtin_amdgcn_global_load_lds((gbl_vp)(size_t)g,
                                   (lds_vp)(uint32_t)(size_t)l,
                                   16, 0, 0);
}

// ---------- prep: W21 [K][N] fp32 -> W21^T [N][K] f16 ----------
__global__ __launch_bounds__(256)
void w21cvt_kernel(const float* __restrict__ W21, _Float16* __restrict__ w21t) {
  __shared__ float sT[64][65];
  const int tid = threadIdx.x;
  const int k0 = blockIdx.x * 64;   // 32
  const int n0 = blockIdx.y * 64;   // 16
  const int row = tid >> 2;
#pragma unroll
  for (int q = 0; q < 4; ++q) {
    int c = (tid & 3) * 4 + q * 16;
    float4 v = *(const float4*)(W21 + (size_t)(k0 + row) * 1024 + n0 + c);
    sT[row][c + 0] = v.x; sT[row][c + 1] = v.y;
    sT[row][c + 2] = v.z; sT[row][c + 3] = v.w;
  }
  __syncthreads();
  const int n  = tid >> 2;
  const int kc = (tid & 3) * 16;
  union { _Float16 h[16]; float4 f4[2]; } u;
#pragma unroll
  for (int e = 0; e < 16; ++e) u.h[e] = (_Float16)sT[kc + e][n];
  float4* dst = (float4*)(w21t + (size_t)(n0 + n) * 2048 + k0 + kc);
  dst[0] = u.f4[0]; dst[1] = u.f4[1];
}

// ---------- gemm1: h = relu(x@W1 + b1), fp32 math, f16 out ----------
__global__ __launch_bounds__(256)
void gemm1_kernel(const float* __restrict__ x, const float* __restrict__ W1,
                  const float* __restrict__ b1, _Float16* __restrict__ hout) {
  __shared__ float sx[64 * 8];
  const int tid = threadIdx.x;
  const int r0 = blockIdx.x * 64;
  if (tid < 128) {
    *(float4*)&sx[tid * 4] = *(const float4*)(x + (size_t)r0 * 8 + tid * 4);
  }
  float w1r[8][8];
#pragma unroll
  for (int j = 0; j < 8; ++j) {
    *(float4*)&w1r[j][0] = *(const float4*)(W1 + j * 2048 + tid * 8);
    *(float4*)&w1r[j][4] = *(const float4*)(W1 + j * 2048 + tid * 8 + 4);
  }
  float bb[8];
  *(float4*)&bb[0] = *(const float4*)(b1 + tid * 8);
  *(float4*)&bb[4] = *(const float4*)(b1 + tid * 8 + 4);
  __syncthreads();
  for (int r = 0; r < 64; ++r) {
    float xv[8];
    *(float4*)&xv[0] = *(float4*)&sx[r * 8];
    *(float4*)&xv[4] = *(float4*)&sx[r * 8 + 4];
    float acc[8];
#pragma unroll
    for (int c = 0; c < 8; ++c) acc[c] = bb[c];
#pragma unroll
    for (int j = 0; j < 8; ++j)
#pragma unroll
      for (int c = 0; c < 8; ++c) acc[c] = fmaf(xv[j], w1r[j][c], acc[c]);
    union { f16x8 v; float4 f4; } u;
#pragma unroll
    for (int c = 0; c < 8; ++c) u.v[c] = (_Float16)fmaxf(acc[c], 0.f);
    *(float4*)(hout + (size_t)(r0 + r) * 2048 + tid * 8) = u.f4;
  }
}

// ---------- gemm2: 256x256, BK=64, 4-phase/tile schedule, counted vmcnt ----------
// LDS per buffer (64 KiB): [A_s0 16K][A_s1 16K][B_s0 16K][B_s1 16K]; 2 buffers.
// Region layout: [256 rows][4 slots x 16B], slot = (chunk + (row>>1)) & 3.
__global__ __launch_bounds__(512, 2)
void gemm2_kernel(const _Float16* __restrict__ h, const _Float16* __restrict__ w21t,
                  const float* __restrict__ b21, const float* __restrict__ w31,
                  float* __restrict__ part) {
  __shared__ __align__(16) char smem[131072];

  const int tid  = threadIdx.x;
  const int lane = tid & 63;
  const int w    = tid >> 6;      // 0..7
  const int wr   = w >> 2;        // 0..1 -> 128 rows each
  const int wc   = w & 3;         // 0..3 -> 64 cols each

  // XCD-chunked bijective swizzle (512 % 8 == 0)
  const int lin  = blockIdx.x;
  const int swz  = (lin & 7) * 64 + (lin >> 3);
  const int nblk = swz & 3;
  const int mblk = swz >> 2;
  const int r0 = mblk * BM;
  const int n0 = nblk * BN;

  f32x4 acc[8][4] = {};

  // ---- staging (pre-swizzled global source, linear LDS dest) ----
  // dest (region-local) byte = g*8192 + tid*16 -> row = g*128 + (tid>>2), dslot = tid&3
  // source chunk c = (dslot - (row>>1)) & 3 = ((tid&3) - (tid>>3)) & 3
  const int cA = ((tid & 3) - (tid >> 3)) & 3;
  const _Float16* pA = h    + (size_t)(r0 + (tid >> 2)) * K + cA * 8;
  const _Float16* pB = w21t + (size_t)(n0 + (tid >> 2)) * K + cA * 8;
  char* const lbase = smem + tid * 16;

  auto stageA = [&](int t, int hs) {
    const _Float16* g = pA + t * 64 + hs * 32;
    char* l = lbase + (t & 1) * 65536 + hs * 16384;
    async_ld16(g,                     l);
    async_ld16(g + (size_t)128 * K,   l + 8192);
  };
  auto stageB = [&](int t, int hs) {
    const _Float16* g = pB + t * 64 + hs * 32;
    char* l = lbase + (t & 1) * 65536 + 32768 + hs * 16384;
    async_ld16(g,                     l);
    async_ld16(g + (size_t)128 * K,   l + 8192);
  };

  // ---- ds_read addresses ----
  const int arow0 = wr * 128 + (lane & 15);
  const int aslot = ((lane >> 4) + (arow0 >> 1)) & 3;
  const int abyte = arow0 * 64 + aslot * 16;            // + m*1024, + s*16384
  const int brow0 = wc * 64 + (lane & 15);
  const int bslot = ((lane >> 4) + (brow0 >> 1)) & 3;
  const int bbyte = 32768 + brow0 * 64 + bslot * 16;    // + n*1024, + s*16384

  // ---- prologue: Bs0(0) As0(0) Bs1(0) As1(0) Bs0(1) As0(1) Bs1(1) ----
  stageB(0, 0); stageA(0, 0); stageB(0, 1); stageA(0, 1);
  stageB(1, 0); stageA(1, 0); stageB(1, 1);
  asm volatile("s_waitcnt vmcnt(10)" ::: "memory");
  __builtin_amdgcn_s_barrier();

  for (int t = 0; t < NT; ++t) {
    const char* base = smem + (t & 1) * 65536;
    f16x8 aF[4], bF[4];

    // ---- ph0: read A s0 m0-3 + B s0 n0-3; stage As1(t+1); MFMA m0-3 ----
#pragma unroll
    for (int m = 0; m < 4; ++m) aF[m] = *(const f16x8*)(base + abyte + m * 1024);
#pragma unroll
    for (int n = 0; n < 4; ++n) bF[n] = *(const f16x8*)(base + bbyte + n * 1024);
    if (t + 1 < NT) stageA(t + 1, 1);
    __builtin_amdgcn_s_barrier();
    asm volatile("s_waitcnt lgkmcnt(0)" ::: "memory");
    __builtin_amdgcn_sched_barrier(0);
    __builtin_amdgcn_s_setprio(1);
#pragma unroll
    for (int m = 0; m < 4; ++m)
#pragma unroll
      for (int n = 0; n < 4; ++n)
        acc[m][n] = __builtin_amdgcn_mfma_f32_16x16x32_f16(aF[m], bF[n], acc[m][n], 0, 0, 0);
    __builtin_amdgcn_s_setprio(0);
    __builtin_amdgcn_sched_barrier(0);
    __builtin_amdgcn_s_barrier();

    // ---- ph1: read A s0 m4-7; stage Bs0(t+2); vmcnt; MFMA m4-7 ----
#pragma unroll
    for (int m = 0; m < 4; ++m) aF[m] = *(const f16x8*)(base + abyte + (m + 4) * 1024);
    if (t + 2 < NT) stageB(t + 2, 0);
    if (t < NT - 2) asm volatile("s_waitcnt vmcnt(10)" ::: "memory");
    else            asm volatile("s_waitcnt vmcnt(0)"  ::: "memory");
    __builtin_amdgcn_s_barrier();
    asm volatile("s_waitcnt lgkmcnt(0)" ::: "memory");
    __builtin_amdgcn_sched_barrier(0);
    __builtin_amdgcn_s_setprio(1);
#pragma unroll
    for (int m = 0; m < 4; ++m)
#pragma unroll
      for (int n = 0; n < 4; ++n)
        acc[m + 4][n] = __builtin_amdgcn_mfma_f32_16x16x32_f16(aF[m], bF[n], acc[m + 4][n], 0, 0, 0);
    __builtin_amdgcn_s_setprio(0);
    __builtin_amdgcn_sched_barrier(0);
    __builtin_amdgcn_s_barrier();

    // ---- ph2: read A s1 m0-3 + B s1 n0-3; stage As0(t+2); MFMA m0-3 ----
#pragma unroll
    for (int m = 0; m < 4; ++m) aF[m] = *(const f16x8*)(base + 16384 + abyte + m * 1024);
#pragma unroll
    for (int n = 0; n < 4; ++n) bF[n] = *(const f16x8*)(base + 16384 + bbyte + n * 1024);
    if (t + 2 < NT) stageA(t + 2, 0);
    __builtin_amdgcn_s_barrier();
    asm volatile("s_waitcnt lgkmcnt(0)" ::: "memory");
    __builtin_amdgcn_sched_barrier(0);
    __builtin_amdgcn_s_setprio(1);
#pragma unroll
    for (int m = 0; m < 4; ++m)
#pragma unroll
      for (int n = 0; n < 4; ++n)
        acc[m][n] = __builtin_amdgcn_mfma_f32_16x16x32_f16(aF[m], bF[n], acc[m][n], 0, 0, 0);
    __builtin_amdgcn_s_setprio(0);
    __builtin_amdgcn_sched_barrier(0);
    __builtin_amdgcn_s_barrier();

    // ---- ph3: read A s1 m4-7; stage Bs1(t+2); vmcnt; MFMA m4-7 ----
#pragma unroll
    for (int m = 0; m < 4; ++m) aF[m] = *(const f16x8*)(base + 16384 + abyte + (m + 4) * 1024);
    if (t + 2 < NT) stageB(t + 2, 1);
    if (t < NT - 2) asm volatile("s_waitcnt vmcnt(10)" ::: "memory");
    else            asm volatile("s_waitcnt vmcnt(0)"  ::: "memory");
    __builtin_amdgcn_s_barrier();
    asm volatile("s_waitcnt lgkmcnt(0)" ::: "memory");
    __builtin_amdgcn_sched_barrier(0);
    __builtin_amdgcn_s_setprio(1);
#pragma unroll
    for (int m = 0; m < 4; ++m)
#pragma unroll
      for (int n = 0; n < 4; ++n)
        acc[m + 4][n] = __builtin_amdgcn_mfma_f32_16x16x32_f16(aF[m], bF[n], acc[m + 4][n], 0, 0, 0);
    __builtin_amdgcn_s_setprio(0);
    __builtin_amdgcn_sched_barrier(0);
    __builtin_amdgcn_s_barrier();
  }

  // ---- epilogue: a = relu(acc + b21); s = a @ W31; LDS transpose-reduce ----
  float bb[4], w0v[4], w1v[4];
#pragma unroll
  for (int n = 0; n < 4; ++n) {
    int cg = n0 + wc * 64 + n * 16 + (lane & 15);
    bb[n]  = b21[cg];
    w0v[n] = w31[cg * 2 + 0];
    w1v[n] = w31[cg * 2 + 1];
  }
  // write phase: red[w][row_local 0..127][lane&15][2]
  float* red = (float*)smem;
#pragma unroll
  for (int m = 0; m < 8; ++m) {
#pragma unroll
    for (int j = 0; j < 4; ++j) {
      float s0 = 0.f, s1 = 0.f;
#pragma unroll
      for (int n = 0; n < 4; ++n) {
        float a = fmaxf(acc[m][n][j] + bb[n], 0.f);
        s0 = fmaf(a, w0v[n], s0);
        s1 = fmaf(a, w1v[n], s1);
      }
      int row_local = m * 16 + (lane >> 4) * 4 + j;
      int idx = w * 4096 + row_local * 32 + (lane & 15) * 2;
      red[idx]     = s0;
      red[idx + 1] = s1;
    }
  }
  __syncthreads();
  // reduce phase: 1024 (wave,row) slots, 2 per thread
#pragma unroll
  for (int q = tid; q < 1024; q += 512) {
    const int w2 = q >> 7, rl = q & 127;
    const float* src = red + w2 * 4096 + rl * 32;
    float a0 = 0.f, a1 = 0.f;
#pragma unroll
    for (int k = 0; k < 8; ++k) {
      int kk = (k + (tid & 7)) & 7;
      float4 v = *(const float4*)(src + kk * 4);
      a0 += v.x + v.z;
      a1 += v.y + v.w;
    }
    int gr = r0 + (w2 >> 2) * 128 + rl;
    int strip = nblk * 4 + (w2 & 3);
    float2 o; o.x = a0; o.y = a1;
    *(float2*)(part + ((size_t)strip * M + gr) * 2) = o;
  }
}

// ---------- final: sum strips, add b31, QP clip, de/normalize ----------
__global__ __launch_bounds__(256)
void final_kernel(const float* __restrict__ part, const float* __restrict__ b31,
                  const float* __restrict__ om, const float* __restrict__ os,
                  const float* __restrict__ s0p, const float* __restrict__ s1p,
                  const float* __restrict__ s2p, const float* __restrict__ s3p,
                  float* __restrict__ out) {
  const int r = blockIdx.x * blockDim.x + threadIdx.x;
  float a0 = b31[0], a1 = b31[1];
#pragma unroll
  for (int s = 0; s < NSTRIP; ++s) {
    float2 v = *(const float2*)(part + ((size_t)s * M + r) * 2);
    a0 += v.x; a1 += v.y;
  }
  const float om0 = om[0], om1 = om[1], os0 = os[0], os1 = os[1];
  const float xa0 = a0 * os0 + om0;
  const float xa1 = a1 * os1 + om1;
  const float up0 = 1.0f + s2p[0];            // OMEGA_LIMIT + s2
  const float up1 = 1.0f + s0p[0];            // ACCEL_LIMIT + s0
  const float lo0 = -(1.0f + s3p[0]);
  const float lo1 = -(1.0f + s1p[0]);
  const float u0 = fminf(fmaxf(-xa0, lo0), up0);
  const float u1 = fminf(fmaxf(-xa1, lo1), up1);
  float2 o; o.x = (u0 - om0) / os0; o.y = (u1 - om1) / os1;
  *(float2*)(out + (size_t)r * 2) = o;
}

extern "C" void kernel_launch(void* const* d_in, const int* in_sizes, int n_in,
                              void* d_out, int out_size, void* d_ws, size_t ws_size,
                              hipStream_t stream) {
  const float* x    = (const float*)d_in[0];
  const float* W1   = (const float*)d_in[1];
  const float* b1   = (const float*)d_in[2];
  const float* W21  = (const float*)d_in[3];
  const float* b21  = (const float*)d_in[4];
  const float* W31  = (const float*)d_in[5];
  const float* b31  = (const float*)d_in[6];
  const float* omean = (const float*)d_in[13];
  const float* ostd  = (const float*)d_in[14];
  const float* s0 = (const float*)d_in[15];
  const float* s1 = (const float*)d_in[16];
  const float* s2 = (const float*)d_in[17];
  const float* s3 = (const float*)d_in[18];
  float* out = (float*)d_out;

  char* ws = (char*)d_ws;
  _Float16* hbuf = (_Float16*)(ws + WS_H);
  _Float16* w21t = (_Float16*)(ws + WS_W21T);
  float*    part = (float*)(ws + WS_PART);

  w21cvt_kernel<<<dim3(32, 16), dim3(256), 0, stream>>>(W21, w21t);
  gemm1_kernel<<<dim3(512), dim3(256), 0, stream>>>(x, W1, b1, hbuf);
  gemm2_kernel<<<dim3((M / BM) * (N / BN)), dim3(512), 0, stream>>>(hbuf, w21t, b21, W31, part);
  final_kernel<<<dim3(M / 256), dim3(256), 0, stream>>>(part, b31, omean, ostd,
                                                        s0, s1, s2, s3, out);
}

// Round 4
// 151.790 us; speedup vs baseline: 1.3945x; 1.0035x over previous
//
#include <hip/hip_runtime.h>
#include <hip/hip_bf16.h>
#include <hip/hip_fp16.h>

#define DEVI __device__ __forceinline__

typedef _Float16 f16x8 __attribute__((ext_vector_type(8)));
typedef float f32x4 __attribute__((ext_vector_type(4)));

static constexpr int M = 32768;   // batch
static constexpr int N = 1024;    // H21
static constexpr int K = 2048;    // H1
static constexpr int BM = 256, BN = 256, BK = 64;
static constexpr int NT = K / BK;            // 32 k-tiles
static constexpr int NSTRIP = (N / BN) * 4;  // 16 partial strips

// ---- ws layout ----
static constexpr size_t WS_H    = 0;                       // f16 [M][K]
static constexpr size_t WS_W21T = 134217728;               // f16 [N][K]
static constexpr size_t WS_PART = 134217728 + 4194304;     // f32 [16][M][2]

using lds_vp = __attribute__((address_space(3))) void*;
using gbl_vp = const __attribute__((address_space(1))) void*;

DEVI void async_ld16(const void* g, void* l) {
  __builtin_amdgcn_global_load_lds((gbl_vp)(size_t)g,
                                   (lds_vp)(uint32_t)(size_t)l,
                                   16, 0, 0);
}

// ---------- prep: W21 [K][N] fp32 -> W21^T [N][K] f16 ----------
__global__ __launch_bounds__(256)
void w21cvt_kernel(const float* __restrict__ W21, _Float16* __restrict__ w21t) {
  __shared__ float sT[64][65];
  const int tid = threadIdx.x;
  const int k0 = blockIdx.x * 64;
  const int n0 = blockIdx.y * 64;
  const int row = tid >> 2;
#pragma unroll
  for (int q = 0; q < 4; ++q) {
    int c = (tid & 3) * 4 + q * 16;
    float4 v = *(const float4*)(W21 + (size_t)(k0 + row) * 1024 + n0 + c);
    sT[row][c + 0] = v.x; sT[row][c + 1] = v.y;
    sT[row][c + 2] = v.z; sT[row][c + 3] = v.w;
  }
  __syncthreads();
  const int n  = tid >> 2;
  const int kc = (tid & 3) * 16;
  union { _Float16 h[16]; float4 f4[2]; } u;
#pragma unroll
  for (int e = 0; e < 16; ++e) u.h[e] = (_Float16)sT[kc + e][n];
  float4* dst = (float4*)(w21t + (size_t)(n0 + n) * 2048 + k0 + kc);
  dst[0] = u.f4[0]; dst[1] = u.f4[1];
}

// ---------- gemm1: h = relu(x@W1 + b1), fp32 math, f16 out ----------
__global__ __launch_bounds__(256)
void gemm1_kernel(const float* __restrict__ x, const float* __restrict__ W1,
                  const float* __restrict__ b1, _Float16* __restrict__ hout) {
  __shared__ float sx[64 * 8];
  const int tid = threadIdx.x;
  const int r0 = blockIdx.x * 64;
  if (tid < 128) {
    *(float4*)&sx[tid * 4] = *(const float4*)(x + (size_t)r0 * 8 + tid * 4);
  }
  float w1r[8][8];
#pragma unroll
  for (int j = 0; j < 8; ++j) {
    *(float4*)&w1r[j][0] = *(const float4*)(W1 + j * 2048 + tid * 8);
    *(float4*)&w1r[j][4] = *(const float4*)(W1 + j * 2048 + tid * 8 + 4);
  }
  float bb[8];
  *(float4*)&bb[0] = *(const float4*)(b1 + tid * 8);
  *(float4*)&bb[4] = *(const float4*)(b1 + tid * 8 + 4);
  __syncthreads();
  for (int r = 0; r < 64; ++r) {
    float xv[8];
    *(float4*)&xv[0] = *(float4*)&sx[r * 8];
    *(float4*)&xv[4] = *(float4*)&sx[r * 8 + 4];
    float acc[8];
#pragma unroll
    for (int c = 0; c < 8; ++c) acc[c] = bb[c];
#pragma unroll
    for (int j = 0; j < 8; ++j)
#pragma unroll
      for (int c = 0; c < 8; ++c) acc[c] = fmaf(xv[j], w1r[j][c], acc[c]);
    union { f16x8 v; float4 f4; } u;
#pragma unroll
    for (int c = 0; c < 8; ++c) u.v[c] = (_Float16)fmaxf(acc[c], 0.f);
    *(float4*)(hout + (size_t)(r0 + r) * 2048 + tid * 8) = u.f4;
  }
}

// ---------- gemm2: 256x256, BK=64, 4-phase + 1-phase-lookahead reg pipeline ----------
__global__ __launch_bounds__(512, 2)
void gemm2_kernel(const _Float16* __restrict__ h, const _Float16* __restrict__ w21t,
                  const float* __restrict__ b21, const float* __restrict__ w31,
                  float* __restrict__ part) {
  __shared__ __align__(16) char smem[131072];

  const int tid  = threadIdx.x;
  const int lane = tid & 63;
  const int w    = tid >> 6;
  const int wr   = w >> 2;
  const int wc   = w & 3;

  const int lin  = blockIdx.x;
  const int swz  = (lin & 7) * 64 + (lin >> 3);
  const int nblk = swz & 3;
  const int mblk = swz >> 2;
  const int r0 = mblk * BM;
  const int n0 = nblk * BN;

  f32x4 acc[8][4] = {};

  // staging (pre-swizzled global source, linear LDS dest)
  const int cA = ((tid & 3) - (tid >> 3)) & 3;
  const _Float16* pA = h    + (size_t)(r0 + (tid >> 2)) * K + cA * 8;
  const _Float16* pB = w21t + (size_t)(n0 + (tid >> 2)) * K + cA * 8;
  char* const lbase = smem + tid * 16;

  auto stageA = [&](int t, int hs) {
    const _Float16* g = pA + t * 64 + hs * 32;
    char* l = lbase + (t & 1) * 65536 + hs * 16384;
    async_ld16(g,                     l);
    async_ld16(g + (size_t)128 * K,   l + 8192);
  };
  auto stageB = [&](int t, int hs) {
    const _Float16* g = pB + t * 64 + hs * 32;
    char* l = lbase + (t & 1) * 65536 + 32768 + hs * 16384;
    async_ld16(g,                     l);
    async_ld16(g + (size_t)128 * K,   l + 8192);
  };

  // ds_read addresses (swizzled)
  const int arow0 = wr * 128 + (lane & 15);
  const int aslot = ((lane >> 4) + (arow0 >> 1)) & 3;
  const int abyte = arow0 * 64 + aslot * 16;
  const int brow0 = wc * 64 + (lane & 15);
  const int bslot = ((lane >> 4) + (brow0 >> 1)) & 3;
  const int bbyte = 32768 + brow0 * 64 + bslot * 16;

  auto rdA4 = [&](f16x8* d, const char* basep, int sh, int mlo) {
#pragma unroll
    for (int m = 0; m < 4; ++m)
      d[m] = *(const f16x8*)(basep + sh * 16384 + abyte + (mlo + m) * 1024);
  };
  auto rdB4 = [&](f16x8* d, const char* basep, int sh) {
#pragma unroll
    for (int n = 0; n < 4; ++n)
      d[n] = *(const f16x8*)(basep + sh * 16384 + bbyte + n * 1024);
  };
  auto mm = [&](const f16x8* a, const f16x8* b, int moff) {
#pragma unroll
    for (int m = 0; m < 4; ++m)
#pragma unroll
      for (int n = 0; n < 4; ++n)
        acc[m + moff][n] =
            __builtin_amdgcn_mfma_f32_16x16x32_f16(a[m], b[n], acc[m + moff][n], 0, 0, 0);
  };

#define SB __builtin_amdgcn_sched_barrier(0)
#define BAR __builtin_amdgcn_s_barrier()
#define LGKM(nn) asm volatile("s_waitcnt lgkmcnt(" #nn ")" ::: "memory")

  f16x8 ar0[4], ar1[4], br0[4], br1[4];

  // ---- prologue ----
  stageB(0, 0); stageA(0, 0); stageB(0, 1); stageA(0, 1);
  stageB(1, 0); stageA(1, 0); stageB(1, 1);
  asm volatile("s_waitcnt vmcnt(10)" ::: "memory");   // As0(0),Bs0(0) resident
  BAR;
  {
    const char* b0 = smem;
    rdA4(ar0, b0, 0, 0);      // A s0 m0-3 (t=0)
    rdB4(br0, b0, 0);         // B s0      (t=0)
  }

  for (int t = 0; t < NT - 1; ++t) {
    const char* base  = smem + (t & 1) * 65536;
    const char* baseN = smem + ((t + 1) & 1) * 65536;

    // ---- Phase A: prefetch A s0 m4-7; MFMA P0 = (ar0, br0) -> acc[0..3] ----
    rdA4(ar1, base, 0, 4);
    stageA(t + 1, 1);
    SB;
    BAR; LGKM(4); SB;
    __builtin_amdgcn_s_setprio(1);
    mm(ar0, br0, 0);
    __builtin_amdgcn_s_setprio(0); SB;
    BAR;

    // ---- Phase B: vmcnt; prefetch A s1 m0-3 + B s1; MFMA P1 = (ar1, br0) -> acc[4..7] ----
    if (t + 2 < NT) stageB(t + 2, 0);
    if (t < NT - 2) asm volatile("s_waitcnt vmcnt(10)" ::: "memory");
    else            asm volatile("s_waitcnt vmcnt(0)"  ::: "memory");
    rdA4(ar0, base, 1, 0);
    rdB4(br1, base, 1);
    SB;
    BAR; LGKM(8); SB;
    __builtin_amdgcn_s_setprio(1);
    mm(ar1, br0, 4);
    __builtin_amdgcn_s_setprio(0); SB;
    BAR;

    // ---- Phase C: prefetch A s1 m4-7; MFMA P2 = (ar0, br1) -> acc[0..3] ----
    rdA4(ar1, base, 1, 4);
    if (t + 2 < NT) stageA(t + 2, 0);
    SB;
    BAR; LGKM(4); SB;
    __builtin_amdgcn_s_setprio(1);
    mm(ar0, br1, 0);
    __builtin_amdgcn_s_setprio(0); SB;
    BAR;

    // ---- Phase D: vmcnt; prefetch next tile A s0 m0-3 + B s0; MFMA P3 = (ar1, br1) -> acc[4..7] ----
    if (t + 2 < NT) stageB(t + 2, 1);
    if (t < NT - 2) asm volatile("s_waitcnt vmcnt(10)" ::: "memory");
    else            asm volatile("s_waitcnt vmcnt(0)"  ::: "memory");
    rdA4(ar0, baseN, 0, 0);
    rdB4(br0, baseN, 0);
    SB;
    BAR; LGKM(8); SB;
    __builtin_amdgcn_s_setprio(1);
    mm(ar1, br1, 4);
    __builtin_amdgcn_s_setprio(0); SB;
    BAR;
  }

  // ---- peeled last tile (no staging; ar0/br0 pre-filled) ----
  {
    const char* base = smem + ((NT - 1) & 1) * 65536;

    rdA4(ar1, base, 0, 4);
    SB; BAR; LGKM(4); SB;
    __builtin_amdgcn_s_setprio(1); mm(ar0, br0, 0); __builtin_amdgcn_s_setprio(0); SB;
    BAR;

    rdA4(ar0, base, 1, 0);
    rdB4(br1, base, 1);
    SB; BAR; LGKM(8); SB;
    __builtin_amdgcn_s_setprio(1); mm(ar1, br0, 4); __builtin_amdgcn_s_setprio(0); SB;
    BAR;

    rdA4(ar1, base, 1, 4);
    SB; BAR; LGKM(4); SB;
    __builtin_amdgcn_s_setprio(1); mm(ar0, br1, 0); __builtin_amdgcn_s_setprio(0); SB;
    BAR;

    LGKM(0); SB;
    __builtin_amdgcn_s_setprio(1); mm(ar1, br1, 4); __builtin_amdgcn_s_setprio(0); SB;
    BAR;
  }

  // ---- epilogue: a = relu(acc + b21); s = a @ W31; LDS transpose-reduce ----
  float bb[4], w0v[4], w1v[4];
#pragma unroll
  for (int n = 0; n < 4; ++n) {
    int cg = n0 + wc * 64 + n * 16 + (lane & 15);
    bb[n]  = b21[cg];
    w0v[n] = w31[cg * 2 + 0];
    w1v[n] = w31[cg * 2 + 1];
  }
  float* red = (float*)smem;
#pragma unroll
  for (int m = 0; m < 8; ++m) {
#pragma unroll
    for (int j = 0; j < 4; ++j) {
      float s0 = 0.f, s1 = 0.f;
#pragma unroll
      for (int n = 0; n < 4; ++n) {
        float a = fmaxf(acc[m][n][j] + bb[n], 0.f);
        s0 = fmaf(a, w0v[n], s0);
        s1 = fmaf(a, w1v[n], s1);
      }
      int row_local = m * 16 + (lane >> 4) * 4 + j;
      int idx = w * 4096 + row_local * 32 + (lane & 15) * 2;
      red[idx]     = s0;
      red[idx + 1] = s1;
    }
  }
  __syncthreads();
#pragma unroll
  for (int q = tid; q < 1024; q += 512) {
    const int w2 = q >> 7, rl = q & 127;
    const float* src = red + w2 * 4096 + rl * 32;
    float a0 = 0.f, a1 = 0.f;
#pragma unroll
    for (int k = 0; k < 8; ++k) {
      int kk = (k + (tid & 7)) & 7;
      float4 v = *(const float4*)(src + kk * 4);
      a0 += v.x + v.z;
      a1 += v.y + v.w;
    }
    int gr = r0 + (w2 >> 2) * 128 + rl;
    int strip = nblk * 4 + (w2 & 3);
    float2 o; o.x = a0; o.y = a1;
    *(float2*)(part + ((size_t)strip * M + gr) * 2) = o;
  }
#undef SB
#undef BAR
#undef LGKM
}

// ---------- final: sum strips, add b31, QP clip, de/normalize ----------
__global__ __launch_bounds__(256)
void final_kernel(const float* __restrict__ part, const float* __restrict__ b31,
                  const float* __restrict__ om, const float* __restrict__ os,
                  const float* __restrict__ s0p, const float* __restrict__ s1p,
                  const float* __restrict__ s2p, const float* __restrict__ s3p,
                  float* __restrict__ out) {
  const int r = blockIdx.x * blockDim.x + threadIdx.x;
  float a0 = b31[0], a1 = b31[1];
#pragma unroll
  for (int s = 0; s < NSTRIP; ++s) {
    float2 v = *(const float2*)(part + ((size_t)s * M + r) * 2);
    a0 += v.x; a1 += v.y;
  }
  const float om0 = om[0], om1 = om[1], os0 = os[0], os1 = os[1];
  const float xa0 = a0 * os0 + om0;
  const float xa1 = a1 * os1 + om1;
  const float up0 = 1.0f + s2p[0];
  const float up1 = 1.0f + s0p[0];
  const float lo0 = -(1.0f + s3p[0]);
  const float lo1 = -(1.0f + s1p[0]);
  const float u0 = fminf(fmaxf(-xa0, lo0), up0);
  const float u1 = fminf(fmaxf(-xa1, lo1), up1);
  float2 o; o.x = (u0 - om0) / os0; o.y = (u1 - om1) / os1;
  *(float2*)(out + (size_t)r * 2) = o;
}

extern "C" void kernel_launch(void* const* d_in, const int* in_sizes, int n_in,
                              void* d_out, int out_size, void* d_ws, size_t ws_size,
                              hipStream_t stream) {
  const float* x    = (const float*)d_in[0];
  const float* W1   = (const float*)d_in[1];
  const float* b1   = (const float*)d_in[2];
  const float* W21  = (const float*)d_in[3];
  const float* b21  = (const float*)d_in[4];
  const float* W31  = (const float*)d_in[5];
  const float* b31  = (const float*)d_in[6];
  const float* omean = (const float*)d_in[13];
  const float* ostd  = (const float*)d_in[14];
  const float* s0 = (const float*)d_in[15];
  const float* s1 = (const float*)d_in[16];
  const float* s2 = (const float*)d_in[17];
  const float* s3 = (const float*)d_in[18];
  float* out = (float*)d_out;

  char* ws = (char*)d_ws;
  _Float16* hbuf = (_Float16*)(ws + WS_H);
  _Float16* w21t = (_Float16*)(ws + WS_W21T);
  float*    part = (float*)(ws + WS_PART);

  w21cvt_kernel<<<dim3(32, 16), dim3(256), 0, stream>>>(W21, w21t);
  gemm1_kernel<<<dim3(512), dim3(256), 0, stream>>>(x, W1, b1, hbuf);
  gemm2_kernel<<<dim3((M / BM) * (N / BN)), dim3(512), 0, stream>>>(hbuf, w21t, b21, W31, part);
  final_kernel<<<dim3(M / 256), dim3(256), 0, stream>>>(part, b31, omean, ostd,
                                                        s0, s1, s2, s3, out);
}